// Round 7
// baseline (240.150 us; speedup 1.0000x reference)
//
#include <hip/hip_runtime.h>

#define NB 32768
#define MAXTILE 1024
#define ROWS 48
#define NT 3
#define XHS 536            // xh stride in u16: 268 dw ≡ 12 mod 32 → phase-minimal LDS access
#define MAGIC1 0x1357A5A5
#define MAGIC2 0x2468C3C3

typedef short s8v __attribute__((ext_vector_type(8)));   // 8 x bf16 bits (4 VGPR)
typedef short s4v __attribute__((ext_vector_type(4)));
typedef float f4v __attribute__((ext_vector_type(4)));
typedef unsigned short u16;
typedef unsigned short u16x4 __attribute__((ext_vector_type(4)));
typedef unsigned int u32;
typedef unsigned char u8;

__device__ __forceinline__ float bf2f(u16 u) { return __uint_as_float(((u32)u) << 16); }
__device__ __forceinline__ u16 f2bf(float f) {
    u32 x = __float_as_uint(f);
    x += 0x7FFFu + ((x >> 16) & 1u);   // RNE
    return (u16)(x >> 16);
}
__device__ __forceinline__ s8v ld8(const u16* p) { return *reinterpret_cast<const s8v*>(p); }

#define MFMA16(a, b, c) __builtin_amdgcn_mfma_f32_16x16x32_bf16((a), (b), (c), 0, 0, 0)

// dtype probe, done locally per block (wave 0 ballot -> LDS). bf16=1, f32=0.
__device__ __forceinline__ void detect_flag(const void* input, int tid, int* shflag)
{
    if (tid < 64) {
        u32 w = ((const u32*)input)[tid];
        u32 h0 = w & 0xFFFFu;
        u32 e0 = (h0 >> 7) & 0xFFu;
        bool plaus = (h0 == 0u) || (e0 >= 96u && e0 <= 143u);
        unsigned long long m = __ballot(plaus);
        if (tid == 0) *shflag = (__popcll(m) >= 48) ? 1 : 0;
    }
}

// ---------------------------------------------------------------------------
// prep_all: ONE dispatch does everything before main.
//   blocks [0,128):   key histogram -> hist table; wait for scanner; scatter
//                     perm + pre-pack sorted feats (bf16)
//   blocks [128,373): weight repack to A-frag layout + bias conversion
//   block  373:       scanner: waits for histograms, scans -> baseTable,
//                     tileInfo; releases scatter phase
// One-way dependency chain + grid (374) << residency capacity => no deadlock.
// ---------------------------------------------------------------------------
struct RepArgs {
    const void* W01; const void* Wp[3]; const void* pre[4]; const void* fin;
    const void* bias[9];
    u16 *rPre, *rW01, *rWp[3], *rFin, *cbias;
};

__global__ __launch_bounds__(256) void prep_kernel(const void* __restrict__ inputv,
                                                   int* __restrict__ hist,       // [128][256]
                                                   int* __restrict__ baseTable,  // [128][256]
                                                   int* __restrict__ dflags,     // [128]
                                                   int* __restrict__ sflag,      // [1]
                                                   int* __restrict__ perm,
                                                   u16* __restrict__ sortedFeats,
                                                   int4* __restrict__ tileInfo,
                                                   RepArgs R)
{
    __shared__ int lcnt[256];
    __shared__ u16 T[8192];
    __shared__ int shmisc;
    int tid = threadIdx.x;
    int b = blockIdx.x;
    detect_flag(inputv, tid, &shmisc);
    __syncthreads();
    int flag = shmisc;
    __syncthreads();

    if (b < 128) {
        // ---- phase 1: histogram
        lcnt[tid] = 0;
        __syncthreads();
        int row = (b << 8) + tid;
        const u32* in32 = (const u32*)inputv;
        const u16* in16 = (const u16*)inputv;
        int key = 0;
#pragma unroll
        for (int j = 0; j < 4; j++) {
            int base = row * 144 + 128 + j * 4;
            u32 v1, v2, v3;
            if (flag) { v1 = in16[base + 1]; v2 = in16[base + 2]; v3 = in16[base + 3]; }
            else      { v1 = in32[base + 1]; v2 = in32[base + 2]; v3 = in32[base + 3]; }
            int m = v1 ? 1 : (v2 ? 2 : (v3 ? 3 : 0));
            key |= m << (j << 1);
        }
        int loc = atomicAdd(&lcnt[key], 1);
        __syncthreads();
        hist[(b << 8) + tid] = lcnt[tid];
        __threadfence();
        __syncthreads();
        if (tid == 0)
            __hip_atomic_store(&dflags[b], MAGIC1, __ATOMIC_RELEASE, __HIP_MEMORY_SCOPE_AGENT);
        // ---- wait for scanner
        if (tid == 0) {
            while (__hip_atomic_load(sflag, __ATOMIC_ACQUIRE, __HIP_MEMORY_SCOPE_AGENT) != MAGIC2)
                __builtin_amdgcn_s_sleep(16);
        }
        __syncthreads();
        __threadfence();
        // ---- phase 2: scatter perm + feats pack
        int dst = baseTable[(b << 8) + key] + loc;
        perm[dst] = row;
        u16* d = sortedFeats + (size_t)dst * 128;
        if (flag) {
            const u16* s = in16 + row * 144;
#pragma unroll
            for (int i = 0; i < 128; i += 8)
                *(s8v*)(d + i) = *(const s8v*)(s + i);
        } else {
            const float* s = (const float*)inputv + row * 144;
#pragma unroll
            for (int i = 0; i < 128; i += 4) {
                f4v f = *(const f4v*)(s + i);
                s4v p;
#pragma unroll
                for (int r = 0; r < 4; r++) p[r] = (short)f2bf(f[r]);
                *(s4v*)(d + i) = p;
            }
        }
        return;
    }

    if (b == 373) {
        // ---- scanner
        if (tid < 128) {
            while (__hip_atomic_load(&dflags[tid], __ATOMIC_ACQUIRE, __HIP_MEMORY_SCOPE_AGENT) != MAGIC1)
                __builtin_amdgcn_s_sleep(16);
        }
        __syncthreads();
        __threadfence();
        int tot = 0;
        for (int b2 = 0; b2 < 128; b2++) tot += hist[(b2 << 8) + tid];
        lcnt[tid] = tot;
        __syncthreads();
        for (int off = 1; off < 256; off <<= 1) {
            int v = (tid >= off) ? lcnt[tid - off] : 0;
            __syncthreads();
            lcnt[tid] += v;
            __syncthreads();
        }
        int gbase = lcnt[tid] - tot;
        {
            int run = gbase;
            for (int b2 = 0; b2 < 128; b2++) {
                baseTable[(b2 << 8) + tid] = run;
                run += hist[(b2 << 8) + tid];
            }
        }
        int tiles = (tot + ROWS - 1) / ROWS;
        __syncthreads();
        lcnt[tid] = tiles;
        __syncthreads();
        for (int off = 1; off < 256; off <<= 1) {
            int v = (tid >= off) ? lcnt[tid - off] : 0;
            __syncthreads();
            lcnt[tid] += v;
            __syncthreads();
        }
        int tbase = lcnt[tid] - tiles;
        int ttot = lcnt[255];
        for (int t = 0; t < tiles; t++) {
            int rem = tot - t * ROWS;
            tileInfo[tbase + t] = make_int4(tid, gbase + t * ROWS, rem > ROWS ? ROWS : rem, 0);
        }
        for (int i = ttot + tid; i < MAXTILE; i += 256)
            tileInfo[i] = make_int4(0, 0, 0, 0);
        __threadfence();
        __syncthreads();
        if (tid == 0)
            __hip_atomic_store(sflag, MAGIC2, __ATOMIC_RELEASE, __HIP_MEMORY_SCOPE_AGENT);
        return;
    }

    // ---- repack path
    int rb = b - 128;
    const void* src = nullptr; u16* dst = nullptr; int K = 0, k0 = 0, mrow = 0;
    if (rb < 32) {
        int m = rb >> 3, s = rb & 7;
        src = R.W01; dst = R.rW01 + (m * 8 + s) * 8192; K = 256; k0 = s * 32; mrow = m;
    } else if (rb < 224) {
        int idx = rb - 32, mat = idx >> 6, r = idx & 63, m = r >> 4, s = r & 15;
        src = R.Wp[mat]; dst = R.rWp[mat] + (m * 16 + s) * 8192; K = 512; k0 = s * 32; mrow = m;
    } else if (rb < 240) {
        int idx = rb - 224, mat = idx >> 2, m = idx & 3;
        src = R.pre[mat]; dst = R.rPre + (mat * 4 + m) * 8192; K = 32; k0 = 0; mrow = m;
    } else if (rb < 244) {
        int m = rb - 240;   // Wfin [m][256][8] -> [m][s8][lane][8], rows l16>=8 zero
        const u16* s16 = (const u16*)R.fin;
        const float* s32 = (const float*)R.fin;
        for (int i = tid; i < 2048; i += 256) {
            int si = (m * 256 + (i >> 3)) * 8 + (i & 7);
            T[i] = flag ? s16[si] : f2bf(s32[si]);
        }
        __syncthreads();
        u16* d = R.rFin + m * 4096;
        for (int i = tid; i < 4096; i += 256) {
            int s = i >> 9, lane = (i >> 3) & 63, j = i & 7;
            int q = lane >> 4, l16 = lane & 15;
            int k = s * 32 + q * 8 + j;
            d[i] = (l16 < 8) ? T[k * 8 + l16] : (u16)0;
        }
        return;
    } else {
        const int sz[9] = {1024,1024,1024,1024,1024,1024,1024,1024,32};
        const int of[9] = {0,1024,2048,3072,4096,5120,6144,7168,8192};
        for (int i = tid; i < 8224; i += 256) {
            int t = i, e = 0;
            while (t >= sz[e]) { t -= sz[e]; e++; }
            R.cbias[of[e] + t] = flag ? ((const u16*)R.bias[e])[t]
                                      : f2bf(((const float*)R.bias[e])[t]);
        }
        return;
    }
    const u16* s16 = (const u16*)src;
    const float* s32 = (const float*)src;
    for (int i = tid; i < 8192; i += 256) {
        int k = i >> 8, n = i & 255;
        int srcIdx = (mrow * K + k0 + k) * 256 + n;
        T[i] = flag ? s16[srcIdx] : f2bf(s32[srcIdx]);
    }
    __syncthreads();
    for (int i = tid; i < 8192; i += 256) {
        int mt = i >> 9, lane = (i >> 3) & 63, j = i & 7;
        int k = ((lane >> 4) << 3) + j, n = (mt << 4) + (lane & 15);
        dst[i] = T[(k << 8) + n];
    }
}

// ---------------------------------------------------------------------------
// main: one block = 48 rows through the whole net (T-formulation).
// 8 waves; wave w: m-tiles {2w,2w+1} x 3 n-tiles. Depth-3 weight prefetch.
// Feats come pre-sorted/pre-packed (bf16) -> full-cache-line reads.
// ---------------------------------------------------------------------------
struct MainP { const u16 *rPre, *rW01, *rWp1, *rWp2, *rWp3, *rFin, *cbias; };

__global__ __launch_bounds__(512, 4) void main_kernel(
    const void* __restrict__ inRaw, const u16* __restrict__ sortedFeats,
    const int* __restrict__ perm, const int4* __restrict__ tileInfo,
    MainP P, void* __restrict__ outp)
{
    __shared__ __align__(16) u16 xh[ROWS * XHS];
    __shared__ int rowids[ROWS];
    __shared__ int shflag;

    int tid = threadIdx.x;
    int lane = tid & 63, w = tid >> 6, quad = lane >> 4, l16 = lane & 15;

    int4 ti = tileInfo[blockIdx.x];
    int key = ti.x, ppos = ti.y, cntIn = ti.z;
    if (cntIn <= 0) return;

    detect_flag(inRaw, tid, &shflag);
    if (tid < ROWS) {
        int g = tid < cntIn ? tid : cntIn - 1;   // clamp partial tile (dups benign)
        rowids[tid] = perm[ppos + g];
    }
    __syncthreads();
    int flag = shflag;
    int fidx[NT];
#pragma unroll
    for (int nt = 0; nt < NT; nt++) {
        int gi = ppos + nt * 16 + l16;
        fidx[nt] = gi < NB ? gi : NB - 1;        // OOB guard for trailing tile
    }
    int mt0 = w << 1, mt1 = mt0 + 1;

    f4v acc0[NT], acc1[NT];

    // 8-slice GEMM half: A slices [0,8) of Abase, B from xh K-slices [ks0, ks0+8)
    auto gemm8 = [&](const u16* Abase, int ks0) {
        s8v A0a = ld8(Abase + (0 * 16 + mt0) * 512 + lane * 8);
        s8v A1a = ld8(Abase + (0 * 16 + mt1) * 512 + lane * 8);
        s8v A0b = ld8(Abase + (1 * 16 + mt0) * 512 + lane * 8);
        s8v A1b = ld8(Abase + (1 * 16 + mt1) * 512 + lane * 8);
        s8v A0c = ld8(Abase + (2 * 16 + mt0) * 512 + lane * 8);
        s8v A1c = ld8(Abase + (2 * 16 + mt1) * 512 + lane * 8);
#pragma unroll
        for (int s = 0; s < 8; s++) {
            s8v c0 = A0a, c1 = A1a;
            A0a = A0b; A1a = A1b; A0b = A0c; A1b = A1c;
            if (s < 5) {
                A0c = ld8(Abase + ((s + 3) * 16 + mt0) * 512 + lane * 8);
                A1c = ld8(Abase + ((s + 3) * 16 + mt1) * 512 + lane * 8);
            }
#pragma unroll
            for (int nt = 0; nt < NT; nt++) {
                s8v B = ld8(&xh[(nt * 16 + l16) * XHS + (ks0 + s) * 32 + quad * 8]);
                acc0[nt] = MFMA16(c0, B, acc0[nt]);
                acc1[nt] = MFMA16(c1, B, acc1[nt]);
            }
        }
    };

    for (int node = 0; node < 4; node++) {
        int m = (key >> (node << 1)) & 3;

        // ---- feats B-frags (pre-packed bf16; one cache line per row per node)
        s8v fb[NT];
#pragma unroll
        for (int nt = 0; nt < NT; nt++)
            fb[nt] = ld8(sortedFeats + (size_t)fidx[nt] * 128 + (node << 5) + (quad << 3));

        // ---- hp^T = relu(Wpre^T @ feats^T + bpre) -> xh[.,256..511]
        const u16* preB = P.rPre + ((node << 2) + m) * 8192;
#pragma unroll
        for (int ci = 0; ci < 2; ci++) {
            int mt = mt0 + ci;
            s8v a = ld8(preB + mt * 512 + lane * 8);
            u16x4 bv = *(const u16x4*)(P.cbias + node * 2048 + m * 256 + mt * 16 + quad * 4);
            f4v bias;
#pragma unroll
            for (int r = 0; r < 4; r++) bias[r] = bf2f(bv[r]);
#pragma unroll
            for (int nt = 0; nt < NT; nt++) {
                f4v c = MFMA16(a, fb[nt], bias);
                s4v p;
#pragma unroll
                for (int r = 0; r < 4; r++) { float v = c[r] > 0.f ? c[r] : 0.f; p[r] = (short)f2bf(v); }
                *(s4v*)&xh[(nt * 16 + l16) * XHS + 256 + mt * 16 + quad * 4] = p;
            }
        }

        // ---- acc init with bpost
        {
            u16x4 b0 = *(const u16x4*)(P.cbias + node * 2048 + 1024 + m * 256 + mt0 * 16 + quad * 4);
            u16x4 b1 = *(const u16x4*)(P.cbias + node * 2048 + 1024 + m * 256 + mt1 * 16 + quad * 4);
            f4v f0, f1;
#pragma unroll
            for (int r = 0; r < 4; r++) { f0[r] = bf2f(b0[r]); f1[r] = bf2f(b1[r]); }
#pragma unroll
            for (int nt = 0; nt < NT; nt++) { acc0[nt] = f0; acc1[nt] = f1; }
        }

        const u16* WB = node ? ((node == 1 ? P.rWp1 : (node == 2 ? P.rWp2 : P.rWp3)) + m * 16 * 8192)
                             : (P.rW01 + m * 8 * 8192);

        // ---- x-part GEMM (reads prev hq in xh[0..255]; no hp dependency)
        if (node) gemm8(WB, 0);
        __syncthreads();                       // hp now visible to all waves
        // ---- hp-part GEMM
        gemm8(node ? (WB + 8 * 8192) : WB, 8);

        // ---- relu + write hq^T -> xh[.,0..255]
#pragma unroll
        for (int ci = 0; ci < 2; ci++) {
            int mt = mt0 + ci;
#pragma unroll
            for (int nt = 0; nt < NT; nt++) {
                f4v a = ci ? acc1[nt] : acc0[nt];
                s4v p;
#pragma unroll
                for (int r = 0; r < 4; r++) { float v = a[r] > 0.f ? a[r] : 0.f; p[r] = (short)f2bf(v); }
                *(s4v*)&xh[(nt * 16 + l16) * XHS + mt * 16 + quad * 4] = p;
            }
        }
        __syncthreads();                       // hq visible; hp region free for next node
    }

    // ---- final: out^T = Wfin^T @ x3^T + bfin (waves 0..NT-1)
    if (w < NT) {
        int m3 = (key >> 6) & 3;
        f4v c;
#pragma unroll
        for (int r = 0; r < 4; r++)
            c[r] = (quad < 2) ? bf2f(P.cbias[8192 + m3 * 8 + quad * 4 + r]) : 0.f;
#pragma unroll
        for (int s = 0; s < 8; s++) {
            s8v A = ld8(P.rFin + m3 * 4096 + s * 512 + lane * 8);
            s8v B = ld8(&xh[(w * 16 + l16) * XHS + s * 32 + quad * 8]);
            c = MFMA16(A, B, c);
        }
        int bidx = w * 16 + l16;
        if (quad < 2 && bidx < cntIn) {
            int row = rowids[bidx];
            if (flag) {
                s4v p;
#pragma unroll
                for (int r = 0; r < 4; r++) p[r] = (short)f2bf(c[r]);
                *(s4v*)((u16*)outp + row * 8 + quad * 4) = p;
            } else {
                *(f4v*)((float*)outp + row * 8 + quad * 4) = c;
            }
        }
    }
}

// ---------------------------------------------------------------------------
extern "C" void kernel_launch(void* const* d_in, const int* in_sizes, int n_in,
                              void* d_out, int out_size, void* d_ws, size_t ws_size,
                              hipStream_t stream)
{
    (void)in_sizes; (void)n_in; (void)out_size;
    const void* input  = d_in[0];
    const void* W00    = d_in[1];
    const void* b00    = d_in[2];
    const void* W01    = d_in[3];
    const void* b01    = d_in[4];
    const void* Wpre1  = d_in[5];
    const void* bpre1  = d_in[6];
    const void* Wpost1 = d_in[7];
    const void* bpost1 = d_in[8];
    const void* Wpre2  = d_in[9];
    const void* bpre2  = d_in[10];
    const void* Wpost2 = d_in[11];
    const void* bpost2 = d_in[12];
    const void* Wpre3  = d_in[13];
    const void* bpre3  = d_in[14];
    const void* Wpost3 = d_in[15];
    const void* bpost3 = d_in[16];
    const void* Wfin   = d_in[17];
    const void* bfin   = d_in[18];

    char* base = (char*)d_ws;
    size_t off = 0;
    auto alloc = [&](size_t bytes) -> char* {
        char* p = base + off;
        off += (bytes + 255) & ~(size_t)255;
        return p;
    };
    int*  hist      = (int*)alloc(128 * 256 * 4);
    int*  baseTable = (int*)alloc(128 * 256 * 4);
    int*  dflags    = (int*)alloc(128 * 4);
    int*  sflag     = (int*)alloc(4);
    int4* tileInfo  = (int4*)alloc(MAXTILE * 16);
    int*  perm      = (int*)alloc((size_t)NB * 4);
    u16*  sortedFeats = (u16*)alloc((size_t)NB * 128 * 2);
    u16*  cbias    = (u16*)alloc(8224 * 2);
    u16*  rPre     = (u16*)alloc(131072 * 2);
    u16*  rW01     = (u16*)alloc(262144 * 2);
    u16*  rWp1     = (u16*)alloc(524288 * 2);
    u16*  rWp2     = (u16*)alloc(524288 * 2);
    u16*  rWp3     = (u16*)alloc(524288 * 2);
    u16*  rFin     = (u16*)alloc(16384 * 2);
    if (off > ws_size) return;

    RepArgs R;
    R.W01 = W01; R.Wp[0] = Wpost1; R.Wp[1] = Wpost2; R.Wp[2] = Wpost3;
    R.pre[0] = W00; R.pre[1] = Wpre1; R.pre[2] = Wpre2; R.pre[3] = Wpre3;
    R.fin = Wfin;
    R.bias[0] = b00;   R.bias[1] = b01;
    R.bias[2] = bpre1; R.bias[3] = bpost1;
    R.bias[4] = bpre2; R.bias[5] = bpost2;
    R.bias[6] = bpre3; R.bias[7] = bpost3;
    R.bias[8] = bfin;
    R.rPre = rPre; R.rW01 = rW01;
    R.rWp[0] = rWp1; R.rWp[1] = rWp2; R.rWp[2] = rWp3;
    R.rFin = rFin; R.cbias = cbias;

    prep_kernel<<<374, 256, 0, stream>>>(input, hist, baseTable, dflags, sflag,
                                         perm, sortedFeats, tileInfo, R);

    MainP P;
    P.rPre = rPre; P.rW01 = rW01; P.rWp1 = rWp1; P.rWp2 = rWp2; P.rWp3 = rWp3;
    P.rFin = rFin; P.cbias = cbias;
    main_kernel<<<MAXTILE, 512, 0, stream>>>(input, sortedFeats, perm, tileInfo, P, d_out);
}

// Round 8
// 203.104 us; speedup vs baseline: 1.1824x; 1.1824x over previous
//
#include <hip/hip_runtime.h>

#define NB 32768
#define MAXTILE 768
#define ROWS 64
#define NT 4
#define XHS 536            // xh stride in u16: 268 dw ≡ 12 mod 32 → phase-minimal LDS access

typedef short s8v __attribute__((ext_vector_type(8)));   // 8 x bf16 bits (4 VGPR)
typedef short s4v __attribute__((ext_vector_type(4)));
typedef float f4v __attribute__((ext_vector_type(4)));
typedef unsigned short u16;
typedef unsigned short u16x4 __attribute__((ext_vector_type(4)));
typedef unsigned int u32;
typedef unsigned char u8;

__device__ __forceinline__ float bf2f(u16 u) { return __uint_as_float(((u32)u) << 16); }
__device__ __forceinline__ u16 f2bf(float f) {
    u32 x = __float_as_uint(f);
    x += 0x7FFFu + ((x >> 16) & 1u);   // RNE
    return (u16)(x >> 16);
}
__device__ __forceinline__ s8v ld8(const u16* p) { return *reinterpret_cast<const s8v*>(p); }

#define MFMA16(a, b, c) __builtin_amdgcn_mfma_f32_16x16x32_bf16((a), (b), (c), 0, 0, 0)

template <int N> struct IC { static constexpr int v = N; };

// dtype probe, done locally per block (wave 0 ballot -> LDS). bf16=1, f32=0.
__device__ __forceinline__ void detect_flag(const void* input, int tid, int* shflag)
{
    if (tid < 64) {
        u32 w = ((const u32*)input)[tid];
        u32 h0 = w & 0xFFFFu;
        u32 e0 = (h0 >> 7) & 0xFFu;
        bool plaus = (h0 == 0u) || (e0 >= 96u && e0 <= 143u);
        unsigned long long m = __ballot(plaus);
        if (tid == 0) *shflag = (__popcll(m) >= 48) ? 1 : 0;
    }
}

// ---------------------------------------------------------------------------
// dispatch A: blocks [0,128): per-block key histogram -> hist[b][256] (plain
// stores, no global atomics, no memset) + keyloc[row] = key | (rank<<8).
// blocks [128,373): weight repack to A-frag layout + bias conversion.
// ---------------------------------------------------------------------------
struct RepArgs {
    const void* W01; const void* Wp[3]; const void* pre[4]; const void* fin;
    const void* bias[9];
    u16 *rPre, *rW01, *rWp[3], *rFin, *cbias;
};

__global__ __launch_bounds__(256) void prepA_kernel(const void* __restrict__ inputv,
                                                    int* __restrict__ hist,       // [128][256]
                                                    u16* __restrict__ keyloc,     // [NB]
                                                    RepArgs R)
{
    __shared__ int lcnt[256];
    __shared__ u16 T[8192];
    __shared__ int shmisc;
    int tid = threadIdx.x;
    int b = blockIdx.x;
    detect_flag(inputv, tid, &shmisc);
    __syncthreads();
    int flag = shmisc;

    if (b < 128) {
        lcnt[tid] = 0;
        __syncthreads();
        int row = (b << 8) + tid;
        const u32* in32 = (const u32*)inputv;
        const u16* in16 = (const u16*)inputv;
        int key = 0;
#pragma unroll
        for (int j = 0; j < 4; j++) {
            int base = row * 144 + 128 + j * 4;
            u32 v1, v2, v3;
            if (flag) { v1 = in16[base + 1]; v2 = in16[base + 2]; v3 = in16[base + 3]; }
            else      { v1 = in32[base + 1]; v2 = in32[base + 2]; v3 = in32[base + 3]; }
            int m = v1 ? 1 : (v2 ? 2 : (v3 ? 3 : 0));
            key |= m << (j << 1);
        }
        int loc = atomicAdd(&lcnt[key], 1);
        keyloc[row] = (u16)(key | (loc << 8));
        __syncthreads();
        hist[(b << 8) + tid] = lcnt[tid];
        return;
    }

    // ---- repack path
    int rb = b - 128;
    const void* src = nullptr; u16* dst = nullptr; int K = 0, k0 = 0, mrow = 0;
    if (rb < 32) {
        int m = rb >> 3, s = rb & 7;
        src = R.W01; dst = R.rW01 + (m * 8 + s) * 8192; K = 256; k0 = s * 32; mrow = m;
    } else if (rb < 224) {
        int idx = rb - 32, mat = idx >> 6, r = idx & 63, m = r >> 4, s = r & 15;
        src = R.Wp[mat]; dst = R.rWp[mat] + (m * 16 + s) * 8192; K = 512; k0 = s * 32; mrow = m;
    } else if (rb < 240) {
        int idx = rb - 224, mat = idx >> 2, m = idx & 3;
        src = R.pre[mat]; dst = R.rPre + (mat * 4 + m) * 8192; K = 32; k0 = 0; mrow = m;
    } else if (rb < 244) {
        int m = rb - 240;   // Wfin [m][256][8] -> [m][s8][lane][8], rows l16>=8 zero
        const u16* s16 = (const u16*)R.fin;
        const float* s32 = (const float*)R.fin;
        for (int i = tid; i < 2048; i += 256) {
            int si = (m * 256 + (i >> 3)) * 8 + (i & 7);
            T[i] = flag ? s16[si] : f2bf(s32[si]);
        }
        __syncthreads();
        u16* d = R.rFin + m * 4096;
        for (int i = tid; i < 4096; i += 256) {
            int s = i >> 9, lane = (i >> 3) & 63, j = i & 7;
            int q = lane >> 4, l16 = lane & 15;
            int k = s * 32 + q * 8 + j;
            d[i] = (l16 < 8) ? T[k * 8 + l16] : (u16)0;
        }
        return;
    } else {
        const int sz[9] = {1024,1024,1024,1024,1024,1024,1024,1024,32};
        const int of[9] = {0,1024,2048,3072,4096,5120,6144,7168,8192};
        for (int i = tid; i < 8224; i += 256) {
            int t = i, e = 0;
            while (t >= sz[e]) { t -= sz[e]; e++; }
            R.cbias[of[e] + t] = flag ? ((const u16*)R.bias[e])[t]
                                      : f2bf(((const float*)R.bias[e])[t]);
        }
        return;
    }
    const u16* s16 = (const u16*)src;
    const float* s32 = (const float*)src;
    for (int i = tid; i < 8192; i += 256) {
        int k = i >> 8, n = i & 255;
        int srcIdx = (mrow * K + k0 + k) * 256 + n;
        T[i] = flag ? s16[srcIdx] : f2bf(s32[srcIdx]);
    }
    __syncthreads();
    for (int i = tid; i < 8192; i += 256) {
        int mt = i >> 9, lane = (i >> 3) & 63, j = i & 7;
        int k = ((lane >> 4) << 3) + j, n = (mt << 4) + (lane & 15);
        dst[i] = T[(k << 8) + n];
    }
}

// ---------------------------------------------------------------------------
// dispatch B: 128 blocks. Each block REDUNDANTLY computes the scan it needs
// from hist (no cross-block dependency, no spin): per-key global base +
// own-block offset. Then scatters perm + packs sorted feats (bf16).
// Block 0 additionally emits the tile table.
// ---------------------------------------------------------------------------
__global__ __launch_bounds__(256) void scatter_kernel(const void* __restrict__ inputv,
                                                      const int* __restrict__ hist,
                                                      const u16* __restrict__ keyloc,
                                                      int* __restrict__ perm,
                                                      u16* __restrict__ sortedFeats,
                                                      int4* __restrict__ tileInfo)
{
    __shared__ int lcnt[256];
    __shared__ int sBase[256];
    __shared__ int shflag;
    int tid = threadIdx.x;
    int b = blockIdx.x;
    detect_flag(inputv, tid, &shflag);
    __syncthreads();
    int flag = shflag;

    int before = 0, tot = 0;
    for (int b2 = 0; b2 < 128; b2++) {
        int h = hist[(b2 << 8) + tid];
        tot += h;
        if (b2 < b) before += h;
    }
    lcnt[tid] = tot;
    __syncthreads();
    for (int off = 1; off < 256; off <<= 1) {
        int v = (tid >= off) ? lcnt[tid - off] : 0;
        __syncthreads();
        lcnt[tid] += v;
        __syncthreads();
    }
    int gbase = lcnt[tid] - tot;
    sBase[tid] = gbase + before;
    __syncthreads();

    if (b == 0) {
        int tiles = (tot + ROWS - 1) / ROWS;
        lcnt[tid] = tiles;
        __syncthreads();
        for (int off = 1; off < 256; off <<= 1) {
            int v = (tid >= off) ? lcnt[tid - off] : 0;
            __syncthreads();
            lcnt[tid] += v;
            __syncthreads();
        }
        int tbase = lcnt[tid] - tiles;
        int ttot = lcnt[255];
        for (int t = 0; t < tiles; t++) {
            int rem = tot - t * ROWS;
            tileInfo[tbase + t] = make_int4(tid, gbase + t * ROWS, rem > ROWS ? ROWS : rem, 0);
        }
        for (int i = ttot + tid; i < MAXTILE; i += 256)
            tileInfo[i] = make_int4(0, 0, 0, 0);
    }

    // ---- scatter + feats pack
    int row = (b << 8) + tid;
    u32 kl = keyloc[row];
    int key = kl & 255, loc = kl >> 8;
    int dst = sBase[key] + loc;
    perm[dst] = row;
    u16* d = sortedFeats + (size_t)dst * 128;
    if (flag) {
        const u16* s = (const u16*)inputv + row * 144;
#pragma unroll
        for (int i = 0; i < 128; i += 8)
            *(s8v*)(d + i) = *(const s8v*)(s + i);
    } else {
        const float* s = (const float*)inputv + row * 144;
#pragma unroll
        for (int i = 0; i < 128; i += 4) {
            f4v f = *(const f4v*)(s + i);
            s4v p;
#pragma unroll
            for (int r = 0; r < 4; r++) p[r] = (short)f2bf(f[r]);
            *(s4v*)(d + i) = p;
        }
    }
}

// ---------------------------------------------------------------------------
// main: one block = 64 rows through the whole net (T-formulation).
// 8 waves; wave w: m-tiles {2w,2w+1} x 4 n-tiles. Fused K=512 gemm (one
// cold-start per node), depth-4 weight prefetch issued BEFORE the barrier.
// ---------------------------------------------------------------------------
struct MainP { const u16 *rPre, *rW01, *rWp1, *rWp2, *rWp3, *rFin, *cbias; };

__global__ __launch_bounds__(512, 4) void main_kernel(
    const void* __restrict__ inRaw, const u16* __restrict__ sortedFeats,
    const int* __restrict__ perm, const int4* __restrict__ tileInfo,
    MainP P, void* __restrict__ outp)
{
    __shared__ __align__(16) u16 xh[ROWS * XHS];
    __shared__ int rowids[ROWS];
    __shared__ int shflag;

    int tid = threadIdx.x;
    int lane = tid & 63, w = tid >> 6, quad = lane >> 4, l16 = lane & 15;

    int4 ti = tileInfo[blockIdx.x];
    int key = ti.x, ppos = ti.y, cntIn = ti.z;
    if (cntIn <= 0) return;

    detect_flag(inRaw, tid, &shflag);
    if (tid < ROWS) {
        int g = tid < cntIn ? tid : cntIn - 1;   // clamp partial tile (dups benign)
        rowids[tid] = perm[ppos + g];
    }
    __syncthreads();
    int flag = shflag;
    int fidx[NT];
#pragma unroll
    for (int nt = 0; nt < NT; nt++) {
        int gi = ppos + nt * 16 + l16;
        fidx[nt] = gi < NB ? gi : NB - 1;        // OOB guard for trailing tile
    }
    int mt0 = w << 1, mt1 = mt0 + 1;

    f4v acc0[NT], acc1[NT];

    // N-slice fused GEMM: prefetch window depth 4, first loads issued BEFORE
    // the hp-visibility barrier (A-frags don't depend on xh).
    auto gemm_run = [&](auto nc, const u16* Ab, int ks0) {
        constexpr int N = decltype(nc)::v;
        constexpr int D = 4;
        const u16* base0 = Ab + mt0 * 512 + lane * 8;
        const u16* base1 = Ab + mt1 * 512 + lane * 8;
        s8v A0[D], A1[D];
#pragma unroll
        for (int d = 0; d < D && d < N; d++) {
            A0[d] = ld8(base0 + d * 8192);
            A1[d] = ld8(base1 + d * 8192);
        }
        __syncthreads();                     // hp/hq now visible; prefetch in flight
#pragma unroll
        for (int s = 0; s < N; s++) {
            s8v c0 = A0[s % D], c1 = A1[s % D];
            if (s + D < N) {
                A0[s % D] = ld8(base0 + (s + D) * 8192);
                A1[s % D] = ld8(base1 + (s + D) * 8192);
            }
#pragma unroll
            for (int nt = 0; nt < NT; nt++) {
                s8v B = ld8(&xh[(nt * 16 + l16) * XHS + (ks0 + s) * 32 + quad * 8]);
                acc0[nt] = MFMA16(c0, B, acc0[nt]);
                acc1[nt] = MFMA16(c1, B, acc1[nt]);
            }
        }
    };

    for (int node = 0; node < 4; node++) {
        int m = (key >> (node << 1)) & 3;

        // ---- feats B-frags (pre-packed bf16, one cache line per row)
        s8v fb[NT];
#pragma unroll
        for (int nt = 0; nt < NT; nt++)
            fb[nt] = ld8(sortedFeats + (size_t)fidx[nt] * 128 + (node << 5) + (quad << 3));

        // ---- hp^T = relu(Wpre^T @ feats^T + bpre) -> xh[.,256..511]
        const u16* preB = P.rPre + ((node << 2) + m) * 8192;
#pragma unroll
        for (int ci = 0; ci < 2; ci++) {
            int mt = mt0 + ci;
            s8v a = ld8(preB + mt * 512 + lane * 8);
            u16x4 bv = *(const u16x4*)(P.cbias + node * 2048 + m * 256 + mt * 16 + quad * 4);
            f4v bias;
#pragma unroll
            for (int r = 0; r < 4; r++) bias[r] = bf2f(bv[r]);
#pragma unroll
            for (int nt = 0; nt < NT; nt++) {
                f4v c = MFMA16(a, fb[nt], bias);
                s4v p;
#pragma unroll
                for (int r = 0; r < 4; r++) { float v = c[r] > 0.f ? c[r] : 0.f; p[r] = (short)f2bf(v); }
                *(s4v*)&xh[(nt * 16 + l16) * XHS + 256 + mt * 16 + quad * 4] = p;
            }
        }

        // ---- acc init with bpost
        {
            u16x4 b0 = *(const u16x4*)(P.cbias + node * 2048 + 1024 + m * 256 + mt0 * 16 + quad * 4);
            u16x4 b1 = *(const u16x4*)(P.cbias + node * 2048 + 1024 + m * 256 + mt1 * 16 + quad * 4);
            f4v f0, f1;
#pragma unroll
            for (int r = 0; r < 4; r++) { f0[r] = bf2f(b0[r]); f1[r] = bf2f(b1[r]); }
#pragma unroll
            for (int nt = 0; nt < NT; nt++) { acc0[nt] = f0; acc1[nt] = f1; }
        }

        // ---- fused K-loop (barrier inside gemm_run, after prefetch issue)
        if (node == 0) gemm_run(IC<8>{},  P.rW01 + m * 8 * 8192, 8);
        else {
            const u16* WB = (node == 1 ? P.rWp1 : (node == 2 ? P.rWp2 : P.rWp3)) + m * 16 * 8192;
            gemm_run(IC<16>{}, WB, 0);
        }
        __syncthreads();                       // all xh reads of this node done

        // ---- relu + write hq^T -> xh[.,0..255]
#pragma unroll
        for (int ci = 0; ci < 2; ci++) {
            int mt = mt0 + ci;
#pragma unroll
            for (int nt = 0; nt < NT; nt++) {
                f4v a = ci ? acc1[nt] : acc0[nt];
                s4v p;
#pragma unroll
                for (int r = 0; r < 4; r++) { float v = a[r] > 0.f ? a[r] : 0.f; p[r] = (short)f2bf(v); }
                *(s4v*)&xh[(nt * 16 + l16) * XHS + mt * 16 + quad * 4] = p;
            }
        }
    }
    __syncthreads();

    // ---- final: out^T = Wfin^T @ x3^T + bfin (waves 0..NT-1)
    if (w < NT) {
        int m3 = (key >> 6) & 3;
        f4v c;
#pragma unroll
        for (int r = 0; r < 4; r++)
            c[r] = (quad < 2) ? bf2f(P.cbias[8192 + m3 * 8 + quad * 4 + r]) : 0.f;
#pragma unroll
        for (int s = 0; s < 8; s++) {
            s8v A = ld8(P.rFin + m3 * 4096 + s * 512 + lane * 8);
            s8v B = ld8(&xh[(w * 16 + l16) * XHS + s * 32 + quad * 8]);
            c = MFMA16(A, B, c);
        }
        int bidx = w * 16 + l16;
        if (quad < 2 && bidx < cntIn) {
            int row = rowids[bidx];
            if (flag) {
                s4v p;
#pragma unroll
                for (int r = 0; r < 4; r++) p[r] = (short)f2bf(c[r]);
                *(s4v*)((u16*)outp + row * 8 + quad * 4) = p;
            } else {
                *(f4v*)((float*)outp + row * 8 + quad * 4) = c;
            }
        }
    }
}

// ---------------------------------------------------------------------------
extern "C" void kernel_launch(void* const* d_in, const int* in_sizes, int n_in,
                              void* d_out, int out_size, void* d_ws, size_t ws_size,
                              hipStream_t stream)
{
    (void)in_sizes; (void)n_in; (void)out_size;
    const void* input  = d_in[0];
    const void* W00    = d_in[1];
    const void* b00    = d_in[2];
    const void* W01    = d_in[3];
    const void* b01    = d_in[4];
    const void* Wpre1  = d_in[5];
    const void* bpre1  = d_in[6];
    const void* Wpost1 = d_in[7];
    const void* bpost1 = d_in[8];
    const void* Wpre2  = d_in[9];
    const void* bpre2  = d_in[10];
    const void* Wpost2 = d_in[11];
    const void* bpost2 = d_in[12];
    const void* Wpre3  = d_in[13];
    const void* bpre3  = d_in[14];
    const void* Wpost3 = d_in[15];
    const void* bpost3 = d_in[16];
    const void* Wfin   = d_in[17];
    const void* bfin   = d_in[18];

    char* base = (char*)d_ws;
    size_t off = 0;
    auto alloc = [&](size_t bytes) -> char* {
        char* p = base + off;
        off += (bytes + 255) & ~(size_t)255;
        return p;
    };
    int*  hist      = (int*)alloc(128 * 256 * 4);
    u16*  keyloc    = (u16*)alloc(NB * 2);
    int4* tileInfo  = (int4*)alloc(MAXTILE * 16);
    int*  perm      = (int*)alloc((size_t)NB * 4);
    u16*  sortedFeats = (u16*)alloc((size_t)NB * 128 * 2);
    u16*  cbias    = (u16*)alloc(8224 * 2);
    u16*  rPre     = (u16*)alloc(131072 * 2);
    u16*  rW01     = (u16*)alloc(262144 * 2);
    u16*  rWp1     = (u16*)alloc(524288 * 2);
    u16*  rWp2     = (u16*)alloc(524288 * 2);
    u16*  rWp3     = (u16*)alloc(524288 * 2);
    u16*  rFin     = (u16*)alloc(16384 * 2);
    if (off > ws_size) return;

    RepArgs R;
    R.W01 = W01; R.Wp[0] = Wpost1; R.Wp[1] = Wpost2; R.Wp[2] = Wpost3;
    R.pre[0] = W00; R.pre[1] = Wpre1; R.pre[2] = Wpre2; R.pre[3] = Wpre3;
    R.fin = Wfin;
    R.bias[0] = b00;   R.bias[1] = b01;
    R.bias[2] = bpre1; R.bias[3] = bpost1;
    R.bias[4] = bpre2; R.bias[5] = bpost2;
    R.bias[6] = bpre3; R.bias[7] = bpost3;
    R.bias[8] = bfin;
    R.rPre = rPre; R.rW01 = rW01;
    R.rWp[0] = rWp1; R.rWp[1] = rWp2; R.rWp[2] = rWp3;
    R.rFin = rFin; R.cbias = cbias;

    prepA_kernel<<<373, 256, 0, stream>>>(input, hist, keyloc, R);
    scatter_kernel<<<128, 256, 0, stream>>>(input, hist, keyloc, perm, sortedFeats, tileInfo);

    MainP P;
    P.rPre = rPre; P.rW01 = rW01; P.rWp1 = rWp1; P.rWp2 = rWp2; P.rWp3 = rWp3;
    P.rFin = rFin; P.cbias = cbias;
    main_kernel<<<MAXTILE, 512, 0, stream>>>(input, sortedFeats, perm, tileInfo, P, d_out);
}

// Round 9
// 194.487 us; speedup vs baseline: 1.2348x; 1.0443x over previous
//
#include <hip/hip_runtime.h>

#define NB 32768
#define MAXTILE 768
#define ROWS 64
#define NT 4
#define XHS 536            // xh stride in u16: 268 dw ≡ 12 mod 32 → phase-minimal LDS access

typedef short s8v __attribute__((ext_vector_type(8)));   // 8 x bf16 bits (4 VGPR)
typedef short s4v __attribute__((ext_vector_type(4)));
typedef float f4v __attribute__((ext_vector_type(4)));
typedef unsigned short u16;
typedef unsigned short u16x4 __attribute__((ext_vector_type(4)));
typedef unsigned int u32;
typedef unsigned char u8;

__device__ __forceinline__ float bf2f(u16 u) { return __uint_as_float(((u32)u) << 16); }
__device__ __forceinline__ u16 f2bf(float f) {
    u32 x = __float_as_uint(f);
    x += 0x7FFFu + ((x >> 16) & 1u);   // RNE
    return (u16)(x >> 16);
}
__device__ __forceinline__ s8v ld8(const u16* p) { return *reinterpret_cast<const s8v*>(p); }

#define MFMA16(a, b, c) __builtin_amdgcn_mfma_f32_16x16x32_bf16((a), (b), (c), 0, 0, 0)

template <int N> struct IC { static constexpr int v = N; };

// dtype probe, done locally per block (wave 0 ballot -> LDS). bf16=1, f32=0.
__device__ __forceinline__ void detect_flag(const void* input, int tid, int* shflag)
{
    if (tid < 64) {
        u32 w = ((const u32*)input)[tid];
        u32 h0 = w & 0xFFFFu;
        u32 e0 = (h0 >> 7) & 0xFFu;
        bool plaus = (h0 == 0u) || (e0 >= 96u && e0 <= 143u);
        unsigned long long m = __ballot(plaus);
        if (tid == 0) *shflag = (__popcll(m) >= 48) ? 1 : 0;
    }
}

// ---------------------------------------------------------------------------
// dispatch A: blocks [0,128): per-block key histogram -> hist[b][256] (plain
// stores, no global atomics, no memset) + keyloc[row] = key | (rank<<8).
// blocks [128,373): weight repack to A-frag layout + bias conversion.
// ---------------------------------------------------------------------------
struct RepArgs {
    const void* W01; const void* Wp[3]; const void* pre[4]; const void* fin;
    const void* bias[9];
    u16 *rPre, *rW01, *rWp[3], *rFin, *cbias;
};

__global__ __launch_bounds__(256) void prepA_kernel(const void* __restrict__ inputv,
                                                    int* __restrict__ hist,       // [128][256]
                                                    u16* __restrict__ keyloc,     // [NB]
                                                    RepArgs R)
{
    __shared__ int lcnt[256];
    __shared__ u16 T[8192];
    __shared__ int shmisc;
    int tid = threadIdx.x;
    int b = blockIdx.x;
    detect_flag(inputv, tid, &shmisc);
    __syncthreads();
    int flag = shmisc;

    if (b < 128) {
        lcnt[tid] = 0;
        __syncthreads();
        int row = (b << 8) + tid;
        const u32* in32 = (const u32*)inputv;
        const u16* in16 = (const u16*)inputv;
        int key = 0;
#pragma unroll
        for (int j = 0; j < 4; j++) {
            int base = row * 144 + 128 + j * 4;
            u32 v1, v2, v3;
            if (flag) { v1 = in16[base + 1]; v2 = in16[base + 2]; v3 = in16[base + 3]; }
            else      { v1 = in32[base + 1]; v2 = in32[base + 2]; v3 = in32[base + 3]; }
            int m = v1 ? 1 : (v2 ? 2 : (v3 ? 3 : 0));
            key |= m << (j << 1);
        }
        int loc = atomicAdd(&lcnt[key], 1);
        keyloc[row] = (u16)(key | (loc << 8));
        __syncthreads();
        hist[(b << 8) + tid] = lcnt[tid];
        return;
    }

    // ---- repack path
    int rb = b - 128;
    const void* src = nullptr; u16* dst = nullptr; int K = 0, k0 = 0, mrow = 0;
    if (rb < 32) {
        int m = rb >> 3, s = rb & 7;
        src = R.W01; dst = R.rW01 + (m * 8 + s) * 8192; K = 256; k0 = s * 32; mrow = m;
    } else if (rb < 224) {
        int idx = rb - 32, mat = idx >> 6, r = idx & 63, m = r >> 4, s = r & 15;
        src = R.Wp[mat]; dst = R.rWp[mat] + (m * 16 + s) * 8192; K = 512; k0 = s * 32; mrow = m;
    } else if (rb < 240) {
        int idx = rb - 224, mat = idx >> 2, m = idx & 3;
        src = R.pre[mat]; dst = R.rPre + (mat * 4 + m) * 8192; K = 32; k0 = 0; mrow = m;
    } else if (rb < 244) {
        int m = rb - 240;   // Wfin [m][256][8] -> [m][s8][lane][8], rows l16>=8 zero
        const u16* s16 = (const u16*)R.fin;
        const float* s32 = (const float*)R.fin;
        for (int i = tid; i < 2048; i += 256) {
            int si = (m * 256 + (i >> 3)) * 8 + (i & 7);
            T[i] = flag ? s16[si] : f2bf(s32[si]);
        }
        __syncthreads();
        u16* d = R.rFin + m * 4096;
        for (int i = tid; i < 4096; i += 256) {
            int s = i >> 9, lane = (i >> 3) & 63, j = i & 7;
            int q = lane >> 4, l16 = lane & 15;
            int k = s * 32 + q * 8 + j;
            d[i] = (l16 < 8) ? T[k * 8 + l16] : (u16)0;
        }
        return;
    } else {
        const int sz[9] = {1024,1024,1024,1024,1024,1024,1024,1024,32};
        const int of[9] = {0,1024,2048,3072,4096,5120,6144,7168,8192};
        for (int i = tid; i < 8224; i += 256) {
            int t = i, e = 0;
            while (t >= sz[e]) { t -= sz[e]; e++; }
            R.cbias[of[e] + t] = flag ? ((const u16*)R.bias[e])[t]
                                      : f2bf(((const float*)R.bias[e])[t]);
        }
        return;
    }
    const u16* s16 = (const u16*)src;
    const float* s32 = (const float*)src;
    for (int i = tid; i < 8192; i += 256) {
        int k = i >> 8, n = i & 255;
        int srcIdx = (mrow * K + k0 + k) * 256 + n;
        T[i] = flag ? s16[srcIdx] : f2bf(s32[srcIdx]);
    }
    __syncthreads();
    for (int i = tid; i < 8192; i += 256) {
        int mt = i >> 9, lane = (i >> 3) & 63, j = i & 7;
        int k = ((lane >> 4) << 3) + j, n = (mt << 4) + (lane & 15);
        dst[i] = T[(k << 8) + n];
    }
}

// ---------------------------------------------------------------------------
// dispatch B (slim): 128 blocks. Redundant per-block scan of hist (no spin,
// no cross-block dependency) -> per-key base; scatter perm only.
// Block 0 additionally emits the tile table.
// ---------------------------------------------------------------------------
__global__ __launch_bounds__(256) void scatter_kernel(const int* __restrict__ hist,
                                                      const u16* __restrict__ keyloc,
                                                      int* __restrict__ perm,
                                                      int4* __restrict__ tileInfo)
{
    __shared__ int lcnt[256];
    __shared__ int sBase[256];
    int tid = threadIdx.x;
    int b = blockIdx.x;

    int before = 0, tot = 0;
    for (int b2 = 0; b2 < 128; b2++) {
        int h = hist[(b2 << 8) + tid];
        tot += h;
        if (b2 < b) before += h;
    }
    lcnt[tid] = tot;
    __syncthreads();
    for (int off = 1; off < 256; off <<= 1) {
        int v = (tid >= off) ? lcnt[tid - off] : 0;
        __syncthreads();
        lcnt[tid] += v;
        __syncthreads();
    }
    int gbase = lcnt[tid] - tot;
    sBase[tid] = gbase + before;
    __syncthreads();

    if (b == 0) {
        int tiles = (tot + ROWS - 1) / ROWS;
        lcnt[tid] = tiles;
        __syncthreads();
        for (int off = 1; off < 256; off <<= 1) {
            int v = (tid >= off) ? lcnt[tid - off] : 0;
            __syncthreads();
            lcnt[tid] += v;
            __syncthreads();
        }
        int tbase = lcnt[tid] - tiles;
        int ttot = lcnt[255];
        for (int t = 0; t < tiles; t++) {
            int rem = tot - t * ROWS;
            tileInfo[tbase + t] = make_int4(tid, gbase + t * ROWS, rem > ROWS ? ROWS : rem, 0);
        }
        for (int i = ttot + tid; i < MAXTILE; i += 256)
            tileInfo[i] = make_int4(0, 0, 0, 0);
    }

    // ---- scatter perm
    int row = (b << 8) + tid;
    u32 kl = keyloc[row];
    int key = kl & 255, loc = kl >> 8;
    perm[sBase[key] + loc] = row;
}

// ---------------------------------------------------------------------------
// main: one block = 64 rows through the whole net (T-formulation).
// 8 waves; wave w: m-tiles {2w,2w+1} x 4 n-tiles. Fused K=512 gemm, depth-4
// weight prefetch issued before the barrier. XCD-aware tile swizzle: block b
// -> tile (b&7)*96 + (b>>3) so each XCD gets a CONTIGUOUS key range (weight
// working set ~2MB fits per-XCD L2; kills cross-XCD weight re-fetch).
// ---------------------------------------------------------------------------
struct MainP { const u16 *rPre, *rW01, *rWp1, *rWp2, *rWp3, *rFin, *cbias; };

__global__ __launch_bounds__(512, 4) void main_kernel(
    const void* __restrict__ inRaw,
    const int* __restrict__ perm, const int4* __restrict__ tileInfo,
    MainP P, void* __restrict__ outp)
{
    __shared__ __align__(16) u16 xh[ROWS * XHS];
    __shared__ int rowids[ROWS];
    __shared__ int shflag;

    int tid = threadIdx.x;
    int lane = tid & 63, w = tid >> 6, quad = lane >> 4, l16 = lane & 15;

    int b = blockIdx.x;
    int t = ((b & 7) * (MAXTILE / 8)) + (b >> 3);   // XCD-contiguous tile runs
    int4 ti = tileInfo[t];
    int key = ti.x, ppos = ti.y, cntIn = ti.z;
    if (cntIn <= 0) return;

    detect_flag(inRaw, tid, &shflag);
    if (tid < ROWS) {
        int g = tid < cntIn ? tid : cntIn - 1;   // clamp partial tile (dups benign)
        rowids[tid] = perm[ppos + g];
    }
    __syncthreads();
    int flag = shflag;
    int rows_[NT];
#pragma unroll
    for (int nt = 0; nt < NT; nt++) rows_[nt] = rowids[nt * 16 + l16];

    const u16* in16 = (const u16*)inRaw;
    const float* in32 = (const float*)inRaw;
    int mt0 = w << 1, mt1 = mt0 + 1;

    f4v acc0[NT], acc1[NT];

    // N-slice fused GEMM: prefetch window depth 4, first loads issued BEFORE
    // the hp-visibility barrier (A-frags don't depend on xh).
    auto gemm_run = [&](auto nc, const u16* Ab, int ks0) {
        constexpr int N = decltype(nc)::v;
        constexpr int D = 4;
        const u16* base0 = Ab + mt0 * 512 + lane * 8;
        const u16* base1 = Ab + mt1 * 512 + lane * 8;
        s8v A0[D], A1[D];
#pragma unroll
        for (int d = 0; d < D && d < N; d++) {
            A0[d] = ld8(base0 + d * 8192);
            A1[d] = ld8(base1 + d * 8192);
        }
        __syncthreads();                     // hp/hq now visible; prefetch in flight
#pragma unroll
        for (int s = 0; s < N; s++) {
            s8v c0 = A0[s % D], c1 = A1[s % D];
            if (s + D < N) {
                A0[s % D] = ld8(base0 + (s + D) * 8192);
                A1[s % D] = ld8(base1 + (s + D) * 8192);
            }
#pragma unroll
            for (int nt = 0; nt < NT; nt++) {
                s8v B = ld8(&xh[(nt * 16 + l16) * XHS + (ks0 + s) * 32 + quad * 8]);
                acc0[nt] = MFMA16(c0, B, acc0[nt]);
                acc1[nt] = MFMA16(c1, B, acc1[nt]);
            }
        }
    };

    for (int node = 0; node < 4; node++) {
        int m = (key >> (node << 1)) & 3;

        // ---- feats B-frags: direct gather (128B contiguous per row per node)
        s8v fb[NT];
#pragma unroll
        for (int nt = 0; nt < NT; nt++) {
            int off = rows_[nt] * 144 + (node << 5) + (quad << 3);
            if (flag) fb[nt] = ld8(in16 + off);
            else {
                f4v f0 = *(const f4v*)(in32 + off);
                f4v f1 = *(const f4v*)(in32 + off + 4);
                s8v r;
#pragma unroll
                for (int j = 0; j < 4; j++) { r[j] = (short)f2bf(f0[j]); r[4 + j] = (short)f2bf(f1[j]); }
                fb[nt] = r;
            }
        }

        // ---- hp^T = relu(Wpre^T @ feats^T + bpre) -> xh[.,256..511]
        const u16* preB = P.rPre + ((node << 2) + m) * 8192;
#pragma unroll
        for (int ci = 0; ci < 2; ci++) {
            int mt = mt0 + ci;
            s8v a = ld8(preB + mt * 512 + lane * 8);
            u16x4 bv = *(const u16x4*)(P.cbias + node * 2048 + m * 256 + mt * 16 + quad * 4);
            f4v bias;
#pragma unroll
            for (int r = 0; r < 4; r++) bias[r] = bf2f(bv[r]);
#pragma unroll
            for (int nt = 0; nt < NT; nt++) {
                f4v c = MFMA16(a, fb[nt], bias);
                s4v p;
#pragma unroll
                for (int r = 0; r < 4; r++) { float v = c[r] > 0.f ? c[r] : 0.f; p[r] = (short)f2bf(v); }
                *(s4v*)&xh[(nt * 16 + l16) * XHS + 256 + mt * 16 + quad * 4] = p;
            }
        }

        // ---- acc init with bpost
        {
            u16x4 b0 = *(const u16x4*)(P.cbias + node * 2048 + 1024 + m * 256 + mt0 * 16 + quad * 4);
            u16x4 b1 = *(const u16x4*)(P.cbias + node * 2048 + 1024 + m * 256 + mt1 * 16 + quad * 4);
            f4v f0, f1;
#pragma unroll
            for (int r = 0; r < 4; r++) { f0[r] = bf2f(b0[r]); f1[r] = bf2f(b1[r]); }
#pragma unroll
            for (int nt = 0; nt < NT; nt++) { acc0[nt] = f0; acc1[nt] = f1; }
        }

        // ---- fused K-loop (barrier inside gemm_run, after prefetch issue)
        if (node == 0) gemm_run(IC<8>{},  P.rW01 + m * 8 * 8192, 8);
        else {
            const u16* WB = (node == 1 ? P.rWp1 : (node == 2 ? P.rWp2 : P.rWp3)) + m * 16 * 8192;
            gemm_run(IC<16>{}, WB, 0);
        }
        __syncthreads();                       // all xh reads of this node done

        // ---- relu + write hq^T -> xh[.,0..255]
#pragma unroll
        for (int ci = 0; ci < 2; ci++) {
            int mt = mt0 + ci;
#pragma unroll
            for (int nt = 0; nt < NT; nt++) {
                f4v a = ci ? acc1[nt] : acc0[nt];
                s4v p;
#pragma unroll
                for (int r = 0; r < 4; r++) { float v = a[r] > 0.f ? a[r] : 0.f; p[r] = (short)f2bf(v); }
                *(s4v*)&xh[(nt * 16 + l16) * XHS + mt * 16 + quad * 4] = p;
            }
        }
    }
    __syncthreads();

    // ---- final: out^T = Wfin^T @ x3^T + bfin (waves 0..NT-1)
    if (w < NT) {
        int m3 = (key >> 6) & 3;
        f4v c;
#pragma unroll
        for (int r = 0; r < 4; r++)
            c[r] = (quad < 2) ? bf2f(P.cbias[8192 + m3 * 8 + quad * 4 + r]) : 0.f;
#pragma unroll
        for (int s = 0; s < 8; s++) {
            s8v A = ld8(P.rFin + m3 * 4096 + s * 512 + lane * 8);
            s8v B = ld8(&xh[(w * 16 + l16) * XHS + s * 32 + quad * 8]);
            c = MFMA16(A, B, c);
        }
        int bidx = w * 16 + l16;
        if (quad < 2 && bidx < cntIn) {
            int row = rowids[bidx];
            if (flag) {
                s4v p;
#pragma unroll
                for (int r = 0; r < 4; r++) p[r] = (short)f2bf(c[r]);
                *(s4v*)((u16*)outp + row * 8 + quad * 4) = p;
            } else {
                *(f4v*)((float*)outp + row * 8 + quad * 4) = c;
            }
        }
    }
}

// ---------------------------------------------------------------------------
extern "C" void kernel_launch(void* const* d_in, const int* in_sizes, int n_in,
                              void* d_out, int out_size, void* d_ws, size_t ws_size,
                              hipStream_t stream)
{
    (void)in_sizes; (void)n_in; (void)out_size;
    const void* input  = d_in[0];
    const void* W00    = d_in[1];
    const void* b00    = d_in[2];
    const void* W01    = d_in[3];
    const void* b01    = d_in[4];
    const void* Wpre1  = d_in[5];
    const void* bpre1  = d_in[6];
    const void* Wpost1 = d_in[7];
    const void* bpost1 = d_in[8];
    const void* Wpre2  = d_in[9];
    const void* bpre2  = d_in[10];
    const void* Wpost2 = d_in[11];
    const void* bpost2 = d_in[12];
    const void* Wpre3  = d_in[13];
    const void* bpre3  = d_in[14];
    const void* Wpost3 = d_in[15];
    const void* bpost3 = d_in[16];
    const void* Wfin   = d_in[17];
    const void* bfin   = d_in[18];

    char* base = (char*)d_ws;
    size_t off = 0;
    auto alloc = [&](size_t bytes) -> char* {
        char* p = base + off;
        off += (bytes + 255) & ~(size_t)255;
        return p;
    };
    int*  hist      = (int*)alloc(128 * 256 * 4);
    u16*  keyloc    = (u16*)alloc(NB * 2);
    int4* tileInfo  = (int4*)alloc(MAXTILE * 16);
    int*  perm      = (int*)alloc((size_t)NB * 4);
    u16*  cbias    = (u16*)alloc(8224 * 2);
    u16*  rPre     = (u16*)alloc(131072 * 2);
    u16*  rW01     = (u16*)alloc(262144 * 2);
    u16*  rWp1     = (u16*)alloc(524288 * 2);
    u16*  rWp2     = (u16*)alloc(524288 * 2);
    u16*  rWp3     = (u16*)alloc(524288 * 2);
    u16*  rFin     = (u16*)alloc(16384 * 2);
    if (off > ws_size) return;

    RepArgs R;
    R.W01 = W01; R.Wp[0] = Wpost1; R.Wp[1] = Wpost2; R.Wp[2] = Wpost3;
    R.pre[0] = W00; R.pre[1] = Wpre1; R.pre[2] = Wpre2; R.pre[3] = Wpre3;
    R.fin = Wfin;
    R.bias[0] = b00;   R.bias[1] = b01;
    R.bias[2] = bpre1; R.bias[3] = bpost1;
    R.bias[4] = bpre2; R.bias[5] = bpost2;
    R.bias[6] = bpre3; R.bias[7] = bpost3;
    R.bias[8] = bfin;
    R.rPre = rPre; R.rW01 = rW01;
    R.rWp[0] = rWp1; R.rWp[1] = rWp2; R.rWp[2] = rWp3;
    R.rFin = rFin; R.cbias = cbias;

    prepA_kernel<<<373, 256, 0, stream>>>(input, hist, keyloc, R);
    scatter_kernel<<<128, 256, 0, stream>>>(hist, keyloc, perm, tileInfo);

    MainP P;
    P.rPre = rPre; P.rW01 = rW01; P.rWp1 = rWp1; P.rWp2 = rWp2; P.rWp3 = rWp3;
    P.rFin = rFin; P.cbias = cbias;
    main_kernel<<<MAXTILE, 512, 0, stream>>>(input, perm, tileInfo, P, d_out);
}